// Round 2
// baseline (329.596 us; speedup 1.0000x reference)
//
#include <hip/hip_runtime.h>
#include <hip/hip_bf16.h>
#include <stdint.h>

// SelfAttention1D: B=8,T=2048,D_IN=512,D_ATTN=8,D_OUT=512, scores = (QK^T)^8, softmax, @V
// K0 W_v transpose/cvt -> K1 Q,K high-precision -> K2 V bf16 MFMA GEMM (pre-swizzled tiled
// V layout) -> K3 flash attention: 64-row q-tiles, full 512 cols, per-wave V slices,
// |s|-max prepass, register-prefetched K/V, 1 barrier per 32-key tile.
// Workspace: WvT 512KB @0, Q 512KB @512K, K 512KB @1M, Vg 16MB @1.5M  (~17.6MB total)

typedef float f32x4_t __attribute__((ext_vector_type(4)));
typedef short s16x8_t __attribute__((ext_vector_type(8)));
typedef unsigned int u32;

static __device__ __forceinline__ unsigned short f2bf(float x){
  union { float f; u32 u; } v; v.f = x;
  return (unsigned short)((v.u + 0x7FFFu + ((v.u >> 16) & 1u)) >> 16);
}

static __device__ __forceinline__ u32 pk2bf(float a, float b){
  __hip_bfloat162 h = __float22bfloat162_rn(float2{a, b});
  union { __hip_bfloat162 h2; u32 u; } c; c.h2 = h;
  return c.u;
}

static __device__ __forceinline__ void gload16(const void* g, void* l){
  __builtin_amdgcn_global_load_lds((const __attribute__((address_space(1))) u32*)g,
                                   (__attribute__((address_space(3))) u32*)l, 16, 0, 0);
}

static __device__ __forceinline__ float dot8(const float* q, const float4& a, const float4& b){
  float s = q[0] * a.x;
  s = fmaf(q[1], a.y, s); s = fmaf(q[2], a.z, s); s = fmaf(q[3], a.w, s);
  s = fmaf(q[4], b.x, s); s = fmaf(q[5], b.y, s); s = fmaf(q[6], b.z, s);
  s = fmaf(q[7], b.w, s);
  return s;
}

// ---------------- K0: W_v [512][512] f32 -> WvT [c][d] bf16 ----------------
__global__ __launch_bounds__(256) void k_wvT(const float* __restrict__ Wv,
                                             unsigned short* __restrict__ WvT){
  __shared__ __align__(16) float tile[64][68];
  const int t = threadIdx.x;
  const int dbase = (blockIdx.x >> 3) * 64;
  const int cbase = (blockIdx.x & 7) * 64;
  {
    const int dl = t >> 2, cq = (t & 3) * 16;
    const float* src = Wv + (size_t)(dbase + dl) * 512 + cbase + cq;
#pragma unroll
    for (int i = 0; i < 16; i += 4){
      float4 v = *(const float4*)(src + i);
      tile[dl][cq + i + 0] = v.x; tile[dl][cq + i + 1] = v.y;
      tile[dl][cq + i + 2] = v.z; tile[dl][cq + i + 3] = v.w;
    }
  }
  __syncthreads();
  const int cl = t >> 2, dq = (t & 3) * 16;
  __align__(16) unsigned short o[16];
#pragma unroll
  for (int i = 0; i < 16; ++i) o[i] = f2bf(tile[dq + i][cl]);
  unsigned short* dst = WvT + (size_t)(cbase + cl) * 512 + dbase + dq;
  *(uint4*)dst = *(const uint4*)o;
  *(uint4*)(dst + 8) = *(const uint4*)(o + 8);
}

// ---------------- K1: Q,K fp32 (blocked-fp64 accumulation) ----------------
__global__ __launch_bounds__(256) void k_qk(const float* __restrict__ In,
                                            const float* __restrict__ Wq,
                                            const float* __restrict__ Wk,
                                            float* __restrict__ Qo,
                                            float* __restrict__ Ko){
  __shared__ __align__(16) float wt[16 * 512];
  const int t = threadIdx.x;
#pragma unroll
  for (int i = 0; i < 16; i += 4){
    float4 vq = *(const float4*)(Wq + t * 16 + i);
    float4 vk = *(const float4*)(Wk + t * 16 + i);
    const float* pq = &vq.x;
    const float* pk = &vk.x;
#pragma unroll
    for (int j = 0; j < 4; ++j){
      int flat = t * 16 + i + j;
      int d = flat >> 3, f = flat & 7;
      wt[f * 512 + ((((d >> 2) ^ f) << 2) | (d & 3))] = pq[j];
      int fk = f + 8;
      wt[fk * 512 + ((((d >> 2) ^ (fk & 7)) << 2) | (d & 3))] = pk[j];
    }
  }
  __syncthreads();
  const int tok = blockIdx.x * 16 + (t >> 4);
  const int f = t & 15;
  const float* inrow = In + (size_t)tok * 512;
  const float* wrow = &wt[f * 512];
  const int swz = f & 7;
  double acc = 0.0;
  for (int cb = 0; cb < 128; cb += 8){
    float part = 0.f;
#pragma unroll
    for (int c = cb; c < cb + 8; ++c){
      float4 x = *(const float4*)(inrow + c * 4);
      float4 ww = *(const float4*)(wrow + ((c ^ swz) << 2));
      part = fmaf(x.x, ww.x, part); part = fmaf(x.y, ww.y, part);
      part = fmaf(x.z, ww.z, part); part = fmaf(x.w, ww.w, part);
    }
    acc += (double)part;
  }
  float r = (float)acc;
  if (f < 8) Qo[(size_t)tok * 8 + f] = r;
  else       Ko[(size_t)tok * 8 + (f - 8)] = r;
}

// ---------------- K2: V = In @ Wv, bf16 MFMA, output in swizzled tiled layout ----------
// Vg element addr (shorts): b*1048576 + (s>>5)*16384 + c*32 + (((s>>3)&3)^((c>>1)&3))*8 + (s&7)
__global__ __launch_bounds__(256) void k_vproj(const float* __restrict__ In,
                                               const unsigned short* __restrict__ WvT,
                                               unsigned short* __restrict__ Vg){
  __shared__ __align__(16) char smem[65536];
  char* Ab = smem;
  char* Bb = smem + 16384;
  char* Img = smem + 32768;
  const int t = threadIdx.x;
  const int w = t >> 6, lane = t & 63;
  const int mt = blockIdx.x >> 2, nt = blockIdx.x & 3;
  const int wm = w >> 1, wn = w & 1;
  const int asub = lane & 3;
  int arow[2], acr[2];
#pragma unroll
  for (int i = 0; i < 2; ++i){
    arow[i] = (w * 2 + i) * 16 + (lane >> 2);
    acr[i]  = asub ^ ((arow[i] >> 1) & 3);
  }
  f32x4_t acc[4][4];
#pragma unroll
  for (int m = 0; m < 4; ++m)
#pragma unroll
    for (int n = 0; n < 4; ++n)
      acc[m][n] = (f32x4_t){0.f, 0.f, 0.f, 0.f};

  auto stageB = [&](int kk, int sel){
#pragma unroll
    for (int i = 0; i < 2; ++i){
      int id = w * 2 + i;
      const unsigned short* gb = WvT + (size_t)(nt * 128 + arow[i]) * 512 + kk * 32 + acr[i] * 8;
      gload16(gb, Bb + sel * 8192 + id * 1024);
    }
  };
  auto loadA = [&](int kk, float4* x, float4* y){
#pragma unroll
    for (int i = 0; i < 2; ++i){
      const float* ga = In + (size_t)(mt * 128 + arow[i]) * 512 + kk * 32 + acr[i] * 8;
      x[i] = *(const float4*)ga;
      y[i] = *(const float4*)(ga + 4);
    }
  };
  auto writeA = [&](const float4* x, const float4* y, int sel){
#pragma unroll
    for (int i = 0; i < 2; ++i){
      __align__(16) unsigned short pk[8] = {
        f2bf(x[i].x), f2bf(x[i].y), f2bf(x[i].z), f2bf(x[i].w),
        f2bf(y[i].x), f2bf(y[i].y), f2bf(y[i].z), f2bf(y[i].w)};
      *(uint4*)(Ab + sel * 8192 + arow[i] * 64 + asub * 16) = *(const uint4*)pk;
    }
  };
  {
    float4 x[2], y[2];
    loadA(0, x, y);
    stageB(0, 0);
    writeA(x, y, 0);
    __syncthreads();
  }
  for (int kk = 0; kk < 16; ++kk){
    const int cur = kk & 1;
    float4 x[2], y[2];
    if (kk < 15){
      loadA(kk + 1, x, y);
      stageB(kk + 1, cur ^ 1);
    }
    s16x8_t a[4], bf[4];
#pragma unroll
    for (int m = 0; m < 4; ++m){
      int row = wm * 64 + m * 16 + (lane & 15);
      int chn = (lane >> 4) ^ ((row >> 1) & 3);
      a[m] = *(const s16x8_t*)(Ab + cur * 8192 + row * 64 + chn * 16);
    }
#pragma unroll
    for (int n = 0; n < 4; ++n){
      int col = wn * 64 + n * 16 + (lane & 15);
      int chn = (lane >> 4) ^ ((col >> 1) & 3);
      bf[n] = *(const s16x8_t*)(Bb + cur * 8192 + col * 64 + chn * 16);
    }
#pragma unroll
    for (int m = 0; m < 4; ++m)
#pragma unroll
      for (int n = 0; n < 4; ++n)
        acc[m][n] = __builtin_amdgcn_mfma_f32_16x16x32_bf16(a[m], bf[n], acc[m][n], 0, 0, 0);
    if (kk < 15) writeA(x, y, cur ^ 1);
    __syncthreads();
  }
#pragma unroll
  for (int m = 0; m < 4; ++m){
    int tl = wm * 64 + m * 16 + ((lane >> 4) << 2);
    int sg = tl >> 5;
    int sin = tl & 31;
#pragma unroll
    for (int n = 0; n < 4; ++n){
      int cl = wn * 64 + n * 16 + (lane & 15);
      __align__(8) unsigned short pk2[4];
#pragma unroll
      for (int j = 0; j < 4; ++j) pk2[j] = f2bf(acc[m][n][j]);
      int boff = sg * 8192 + cl * 64 + ((((sin >> 3) & 3) ^ ((cl >> 1) & 3)) << 4) + (sin & 7) * 2;
      *(uint2*)(Img + boff) = *(const uint2*)pk2;
    }
  }
  __syncthreads();
  const size_t bbE = (size_t)(mt >> 4) * 1048576;
  const int tile0 = (mt & 15) * 4;
#pragma unroll
  for (int i = 0; i < 8; ++i){
    int o = (i * 256 + t) * 16;
    int sg = o >> 13, rem = o & 8191;
    unsigned short* dst = Vg + bbE + (size_t)(tile0 + sg) * 16384 + nt * 4096 + (rem >> 1);
    *(uint4*)dst = *(const uint4*)(Img + o);
  }
}

// ---------------- K3: flash attention, 64-row q-tiles x full 512 cols ----------------
// grid 256: b = bid&7 (XCD pin), qt = bid>>3 (32 tiles of 64 rows)
// 8 waves: wave g produces P rows [g*8,g*8+8) and consumes V cols [g*64,g*64+64).
__global__ __launch_bounds__(512, 2) void k_attn(const float* __restrict__ Qg,
                                                 const float* __restrict__ Kg,
                                                 const unsigned short* __restrict__ Vg,
                                                 float* __restrict__ Out){
  __shared__ __align__(16) char smem[41216];
  // V: 8 waves x 4KB @0..32768 ; P: 2 x 4KB @32768..40960 ; lred: 64 f32 @40960
  const int t = threadIdx.x;
  const int g = t >> 6, lane = t & 63;
  const int b = blockIdx.x & 7;
  const int qt = blockIdx.x >> 3;
  const int qbase = qt * 64;
  const int qr = g * 8 + (lane >> 3);   // P row this thread produces (0..63)
  const int ks = lane & 7;              // key sub-slice (4 keys each)

  float qreg[8];
  {
    const float* Qp = Qg + (size_t)(b * 2048 + qbase + qr) * 8;
    float4 a = *(const float4*)Qp;
    float4 c = *(const float4*)(Qp + 4);
    qreg[0] = a.x; qreg[1] = a.y; qreg[2] = a.z; qreg[3] = a.w;
    qreg[4] = c.x; qreg[5] = c.y; qreg[6] = c.z; qreg[7] = c.w;
  }
  const float* Kp = Kg + (size_t)b * (2048 * 8);
  const unsigned short* Vs = Vg + (size_t)b * 1048576 + g * 2048;  // wave's 64-col slice
  char* Vb = smem + g * 4096;           // per-wave V buffer (single)
  char* Pb = smem + 32768;              // P double buffer
  float* lred = (float*)(smem + 40960);

  auto kload = [&](int tt, float4* kr){
    const float* kb = Kp + (size_t)(tt * 32 + ks * 4) * 8;
#pragma unroll
    for (int j = 0; j < 4; ++j){
      kr[2 * j]     = *(const float4*)(kb + j * 8);
      kr[2 * j + 1] = *(const float4*)(kb + j * 8 + 4);
    }
  };
  auto vload = [&](int tt, uint4* vr){
    const unsigned short* src = Vs + (size_t)tt * 16384 + lane * 32;
#pragma unroll
    for (int i = 0; i < 4; ++i) vr[i] = *(const uint4*)(src + i * 8);
  };
  auto vwrite = [&](const uint4* vr){
#pragma unroll
    for (int i = 0; i < 4; ++i) *(uint4*)(Vb + lane * 64 + i * 16) = vr[i];
  };

  // ---- prepass: exact row max of |s| (2-deep K prefetch) ----
  float amax = 0.f;
  {
    float4 ka[8], kb2[8];
    kload(0, ka);
    for (int it = 0; it < 64; it += 2){
      kload(it + 1, kb2);
#pragma unroll
      for (int j = 0; j < 4; ++j)
        amax = fmaxf(amax, fabsf(dot8(qreg, ka[2 * j], ka[2 * j + 1])));
      if (it + 2 < 64) kload(it + 2, ka);
#pragma unroll
      for (int j = 0; j < 4; ++j)
        amax = fmaxf(amax, fabsf(dot8(qreg, kb2[2 * j], kb2[2 * j + 1])));
    }
  }
  amax = fmaxf(amax, __shfl_xor(amax, 1));
  amax = fmaxf(amax, __shfl_xor(amax, 2));
  amax = fmaxf(amax, __shfl_xor(amax, 4));
  float m;
  { float s2 = amax * amax; float s4 = s2 * s2; m = s4 * s4; }
  const float LOG2E = 1.44269504f;
  const float me2 = m * LOG2E;

  float lp = 0.f;
  const int pswz = (ks >> 1) ^ ((qr >> 1) & 3);
  auto score = [&](const float4* kr, int sel){
    float e[4];
#pragma unroll
    for (int j = 0; j < 4; ++j){
      float s = dot8(qreg, kr[2 * j], kr[2 * j + 1]);
      float s2 = s * s; float s4 = s2 * s2; float p = s4 * s4;
      e[j] = exp2f(fmaf(p, LOG2E, -me2));
      lp += e[j];
    }
    uint2 pkd; pkd.x = pk2bf(e[0], e[1]); pkd.y = pk2bf(e[2], e[3]);
    *(uint2*)(Pb + sel * 4096 + qr * 64 + pswz * 16 + (ks & 1) * 8) = pkd;
  };

  // ---- prologue: tile 0 ----
  {
    float4 kr[8]; uint4 vr[4];
    kload(0, kr); vload(0, vr);
    score(kr, 0);
    vwrite(vr);
  }
  __syncthreads();

  f32x4_t acc[4][4];
#pragma unroll
  for (int mm = 0; mm < 4; ++mm)
#pragma unroll
    for (int n = 0; n < 4; ++n)
      acc[mm][n] = (f32x4_t){0.f, 0.f, 0.f, 0.f};

  // ---- main loop: 1 barrier per 32-key tile ----
  for (int tt = 0; tt < 64; ++tt){
    const int cur = tt & 1;
    float4 kr[8]; uint4 vr[4];
    if (tt < 63){ kload(tt + 1, kr); vload(tt + 1, vr); }
    s16x8_t a[4], bf[4];
#pragma unroll
    for (int mm = 0; mm < 4; ++mm){
      int row = mm * 16 + (lane & 15);
      int chn = (lane >> 4) ^ ((row >> 1) & 3);
      a[mm] = *(const s16x8_t*)(Pb + cur * 4096 + row * 64 + chn * 16);
    }
#pragma unroll
    for (int n = 0; n < 4; ++n){
      int cl = n * 16 + (lane & 15);
      int chn = (lane >> 4) ^ ((cl >> 1) & 3);
      bf[n] = *(const s16x8_t*)(Vb + cl * 64 + chn * 16);
    }
#pragma unroll
    for (int mm = 0; mm < 4; ++mm)
#pragma unroll
      for (int n = 0; n < 4; ++n)
        acc[mm][n] = __builtin_amdgcn_mfma_f32_16x16x32_bf16(a[mm], bf[n], acc[mm][n], 0, 0, 0);
    if (tt < 63){
      score(kr, cur ^ 1);   // P for tile tt+1 into other buffer
      vwrite(vr);           // own-wave V for tile tt+1 (after bf reads; lgkm-ordered)
    }
    __syncthreads();
  }

  // ---- softmax denominator ----
  lp += __shfl_xor(lp, 1);
  lp += __shfl_xor(lp, 2);
  lp += __shfl_xor(lp, 4);
  if (ks == 0) lred[qr] = lp;
  __syncthreads();
  float linv[4][4];
#pragma unroll
  for (int mm = 0; mm < 4; ++mm)
#pragma unroll
    for (int j = 0; j < 4; ++j)
      linv[mm][j] = 1.f / lred[mm * 16 + ((lane >> 4) << 2) + j];

  // ---- epilogue: 4 rounds of 16 rows, LDS transpose (stride 516 f32), coalesced stores ----
  float* img = (float*)smem;
#pragma unroll
  for (int mm = 0; mm < 4; ++mm){
#pragma unroll
    for (int n = 0; n < 4; ++n){
      int col = g * 64 + n * 16 + (lane & 15);
#pragma unroll
      for (int j = 0; j < 4; ++j){
        int row_l = ((lane >> 4) << 2) + j;
        img[row_l * 516 + col] = acc[mm][n][j] * linv[mm][j];
      }
    }
    __syncthreads();
#pragma unroll
    for (int it = 0; it < 4; ++it){
      int idx = it * 512 + t;
      int row = idx >> 7, c4 = idx & 127;
      float4 v = *(const float4*)(img + row * 516 + c4 * 4);
      *(float4*)(Out + (size_t)(b * 2048 + qbase + mm * 16 + row) * 512 + c4 * 4) = v;
    }
    __syncthreads();
  }
}

extern "C" void kernel_launch(void* const* d_in, const int* in_sizes, int n_in,
                              void* d_out, int out_size, void* d_ws, size_t ws_size,
                              hipStream_t stream){
  const float* In = (const float*)d_in[0];
  const float* Wq = (const float*)d_in[1];
  const float* Wk = (const float*)d_in[2];
  const float* Wv = (const float*)d_in[3];
  // power (d_in[4]) is the constant 8; hardcoded as three squarings.
  char* ws = (char*)d_ws;
  unsigned short* WvT = (unsigned short*)(ws);
  float* Q            = (float*)(ws + 524288);
  float* K            = (float*)(ws + 1048576);
  unsigned short* Vg  = (unsigned short*)(ws + 1572864);
  float* Out = (float*)d_out;

  hipLaunchKernelGGL(k_wvT,   dim3(64),   dim3(256), 0, stream, Wv, WvT);
  hipLaunchKernelGGL(k_qk,    dim3(1024), dim3(256), 0, stream, In, Wq, Wk, Q, K);
  hipLaunchKernelGGL(k_vproj, dim3(512),  dim3(256), 0, stream, In, WvT, Vg);
  hipLaunchKernelGGL(k_attn,  dim3(256),  dim3(512), 0, stream, Q, K, Vg, Out);
}

// Round 3
// 140.126 us; speedup vs baseline: 2.3521x; 2.3521x over previous
//
#include <hip/hip_runtime.h>
#include <hip/hip_bf16.h>
#include <stdint.h>

// SelfAttention1D: B=8,T=2048,D_IN=512,D_ATTN=8,D_OUT=512, scores=(QK^T)^8, softmax, @V
// K0 W_v transpose/cvt -> K1 Q,K high-precision -> K2 V bf16 MFMA GEMM (V^T tiled layout)
// -> K3 flash attn: 64-row x 256-col blocks (grid 512, 2/CU), KVBLK=64, scalar K loads,
// conflict-free b128 P writes, V fragments direct from L2 (register double-buffered).
// Workspace: WvT 512KB @0, Q 512KB @512K, K 512KB @1M, Vg 16MB @1.5M (~17.6MB total)

typedef float f32x4_t __attribute__((ext_vector_type(4)));
typedef short s16x8_t __attribute__((ext_vector_type(8)));
typedef unsigned int u32;

static __device__ __forceinline__ unsigned short f2bf(float x){
  union { float f; u32 u; } v; v.f = x;
  return (unsigned short)((v.u + 0x7FFFu + ((v.u >> 16) & 1u)) >> 16);
}

static __device__ __forceinline__ u32 pk2bf(float a, float b){
  __hip_bfloat162 h = __float22bfloat162_rn(float2{a, b});
  union { __hip_bfloat162 h2; u32 u; } c; c.h2 = h;
  return c.u;
}

static __device__ __forceinline__ void gload16(const void* g, void* l){
  __builtin_amdgcn_global_load_lds((const __attribute__((address_space(1))) u32*)g,
                                   (__attribute__((address_space(3))) u32*)l, 16, 0, 0);
}

static __device__ __forceinline__ float dot8(const float* q, const float4& a, const float4& b){
  float s = q[0] * a.x;
  s = fmaf(q[1], a.y, s); s = fmaf(q[2], a.z, s); s = fmaf(q[3], a.w, s);
  s = fmaf(q[4], b.x, s); s = fmaf(q[5], b.y, s); s = fmaf(q[6], b.z, s);
  s = fmaf(q[7], b.w, s);
  return s;
}

// ---------------- K0: W_v [512][512] f32 -> WvT [c][d] bf16 ----------------
__global__ __launch_bounds__(256) void k_wvT(const float* __restrict__ Wv,
                                             unsigned short* __restrict__ WvT){
  __shared__ __align__(16) float tile[64][68];
  const int t = threadIdx.x;
  const int dbase = (blockIdx.x >> 3) * 64;
  const int cbase = (blockIdx.x & 7) * 64;
  {
    const int dl = t >> 2, cq = (t & 3) * 16;
    const float* src = Wv + (size_t)(dbase + dl) * 512 + cbase + cq;
#pragma unroll
    for (int i = 0; i < 16; i += 4){
      float4 v = *(const float4*)(src + i);
      tile[dl][cq + i + 0] = v.x; tile[dl][cq + i + 1] = v.y;
      tile[dl][cq + i + 2] = v.z; tile[dl][cq + i + 3] = v.w;
    }
  }
  __syncthreads();
  const int cl = t >> 2, dq = (t & 3) * 16;
  __align__(16) unsigned short o[16];
#pragma unroll
  for (int i = 0; i < 16; ++i) o[i] = f2bf(tile[dq + i][cl]);
  unsigned short* dst = WvT + (size_t)(cbase + cl) * 512 + dbase + dq;
  *(uint4*)dst = *(const uint4*)o;
  *(uint4*)(dst + 8) = *(const uint4*)(o + 8);
}

// ---------------- K1: Q,K fp32 (blocked-fp64 accumulation) ----------------
__global__ __launch_bounds__(256) void k_qk(const float* __restrict__ In,
                                            const float* __restrict__ Wq,
                                            const float* __restrict__ Wk,
                                            float* __restrict__ Qo,
                                            float* __restrict__ Ko){
  __shared__ __align__(16) float wt[16 * 512];
  const int t = threadIdx.x;
#pragma unroll
  for (int i = 0; i < 16; i += 4){
    float4 vq = *(const float4*)(Wq + t * 16 + i);
    float4 vk = *(const float4*)(Wk + t * 16 + i);
    const float* pq = &vq.x;
    const float* pk = &vk.x;
#pragma unroll
    for (int j = 0; j < 4; ++j){
      int flat = t * 16 + i + j;
      int d = flat >> 3, f = flat & 7;
      wt[f * 512 + ((((d >> 2) ^ f) << 2) | (d & 3))] = pq[j];
      int fk = f + 8;
      wt[fk * 512 + ((((d >> 2) ^ (fk & 7)) << 2) | (d & 3))] = pk[j];
    }
  }
  __syncthreads();
  const int tok = blockIdx.x * 16 + (t >> 4);
  const int f = t & 15;
  const float* inrow = In + (size_t)tok * 512;
  const float* wrow = &wt[f * 512];
  const int swz = f & 7;
  double acc = 0.0;
  for (int cb = 0; cb < 128; cb += 8){
    float part = 0.f;
#pragma unroll
    for (int c = cb; c < cb + 8; ++c){
      float4 x = *(const float4*)(inrow + c * 4);
      float4 ww = *(const float4*)(wrow + ((c ^ swz) << 2));
      part = fmaf(x.x, ww.x, part); part = fmaf(x.y, ww.y, part);
      part = fmaf(x.z, ww.z, part); part = fmaf(x.w, ww.w, part);
    }
    acc += (double)part;
  }
  float r = (float)acc;
  if (f < 8) Qo[(size_t)tok * 8 + f] = r;
  else       Ko[(size_t)tok * 8 + (f - 8)] = r;
}

// ---------------- K2: V = In @ Wv, bf16 MFMA, output layout Vg[b][kt][col][k6] ----------
// Vg short offset: b*1048576 + (key>>6)*32768 + col*64 + (key&63)
__global__ __launch_bounds__(256) void k_vproj(const float* __restrict__ In,
                                               const unsigned short* __restrict__ WvT,
                                               unsigned short* __restrict__ Vg){
  __shared__ __align__(16) char smem[65536];
  char* Ab = smem;
  char* Bb = smem + 16384;
  char* Img = smem + 32768;
  const int t = threadIdx.x;
  const int w = t >> 6, lane = t & 63;
  const int mt = blockIdx.x >> 2, nt = blockIdx.x & 3;
  const int wm = w >> 1, wn = w & 1;
  const int asub = lane & 3;
  int arow[2], acr[2];
#pragma unroll
  for (int i = 0; i < 2; ++i){
    arow[i] = (w * 2 + i) * 16 + (lane >> 2);
    acr[i]  = asub ^ ((arow[i] >> 1) & 3);
  }
  f32x4_t acc[4][4];
#pragma unroll
  for (int m = 0; m < 4; ++m)
#pragma unroll
    for (int n = 0; n < 4; ++n)
      acc[m][n] = (f32x4_t){0.f, 0.f, 0.f, 0.f};

  auto stageB = [&](int kk, int sel){
#pragma unroll
    for (int i = 0; i < 2; ++i){
      int id = w * 2 + i;
      const unsigned short* gb = WvT + (size_t)(nt * 128 + arow[i]) * 512 + kk * 32 + acr[i] * 8;
      gload16(gb, Bb + sel * 8192 + id * 1024);
    }
  };
  auto loadA = [&](int kk, float4* x, float4* y){
#pragma unroll
    for (int i = 0; i < 2; ++i){
      const float* ga = In + (size_t)(mt * 128 + arow[i]) * 512 + kk * 32 + acr[i] * 8;
      x[i] = *(const float4*)ga;
      y[i] = *(const float4*)(ga + 4);
    }
  };
  auto writeA = [&](const float4* x, const float4* y, int sel){
#pragma unroll
    for (int i = 0; i < 2; ++i){
      __align__(16) unsigned short pk[8] = {
        f2bf(x[i].x), f2bf(x[i].y), f2bf(x[i].z), f2bf(x[i].w),
        f2bf(y[i].x), f2bf(y[i].y), f2bf(y[i].z), f2bf(y[i].w)};
      *(uint4*)(Ab + sel * 8192 + arow[i] * 64 + asub * 16) = *(const uint4*)pk;
    }
  };
  {
    float4 x[2], y[2];
    loadA(0, x, y);
    stageB(0, 0);
    writeA(x, y, 0);
    __syncthreads();
  }
  for (int kk = 0; kk < 16; ++kk){
    const int cur = kk & 1;
    float4 x[2], y[2];
    if (kk < 15){
      loadA(kk + 1, x, y);
      stageB(kk + 1, cur ^ 1);
    }
    s16x8_t a[4], bf[4];
#pragma unroll
    for (int m = 0; m < 4; ++m){
      int row = wm * 64 + m * 16 + (lane & 15);
      int chn = (lane >> 4) ^ ((row >> 1) & 3);
      a[m] = *(const s16x8_t*)(Ab + cur * 8192 + row * 64 + chn * 16);
    }
#pragma unroll
    for (int n = 0; n < 4; ++n){
      int col = wn * 64 + n * 16 + (lane & 15);
      int chn = (lane >> 4) ^ ((col >> 1) & 3);
      bf[n] = *(const s16x8_t*)(Bb + cur * 8192 + col * 64 + chn * 16);
    }
#pragma unroll
    for (int m = 0; m < 4; ++m)
#pragma unroll
      for (int n = 0; n < 4; ++n)
        acc[m][n] = __builtin_amdgcn_mfma_f32_16x16x32_bf16(a[m], bf[n], acc[m][n], 0, 0, 0);
    if (kk < 15) writeA(x, y, cur ^ 1);
    __syncthreads();
  }
  // epilogue: LDS image of the two 64-key tiles in Vg layout (chunk-XOR-swizzled), linear out
#pragma unroll
  for (int m = 0; m < 4; ++m){
    int r0 = wm * 64 + m * 16 + ((lane >> 4) << 2);
    int kk = r0 >> 6, c8 = (r0 >> 3) & 7, r7 = r0 & 7;
#pragma unroll
    for (int n = 0; n < 4; ++n){
      int cl = wn * 64 + n * 16 + (lane & 15);
      __align__(8) unsigned short pk2[4];
#pragma unroll
      for (int j = 0; j < 4; ++j) pk2[j] = f2bf(acc[m][n][j]);
      int off_sh = kk * 8192 + cl * 64 + ((c8 ^ (cl & 7)) << 3) + r7;
      *(uint2*)(Img + off_sh * 2) = *(const uint2*)pk2;
    }
  }
  __syncthreads();
  const int bq = mt >> 4;
  const int kt0 = (mt & 15) * 2;
#pragma unroll
  for (int i = 0; i < 8; ++i){
    int G = i * 256 + t;                 // 16B granules, 2048 total
    int kk = G >> 10, rem = G & 1023;
    int colL = rem >> 3, k8 = rem & 7;
    const char* src = Img + kk * 16384 + colL * 128 + ((k8 ^ (colL & 7)) << 4);
    unsigned short* dst = Vg + (size_t)bq * 1048576 + (size_t)(kt0 + kk) * 32768
                        + (size_t)(nt * 128 + colL) * 64 + k8 * 8;
    *(uint4*)dst = *(const uint4*)src;
  }
}

// ---------------- K3: flash attention ----------------
// grid 512: b = bid&7 (XCD pin), rr = bid>>3: qt = rr>>1 (64 rows), ch = rr&1 (256 cols)
// 8 waves: lane = q-row; wave g scores keys [8g,8g+8) per 64-key tile (scalar K loads)
// and owns V cols [g*32, g*32+32) (fragments direct from L2, register dbuf).
__global__ __launch_bounds__(512, 4) void k_attn(const float* __restrict__ Qg,
                                                 const float* __restrict__ Kg,
                                                 const unsigned short* __restrict__ Vg,
                                                 float* __restrict__ Out){
  __shared__ __align__(16) char smem[19456];
  // P dbuf 2x8KB @0 ; red 2KB @16896 ; fin 256B @18944 ; epilogue img 16x260 f32 @0
  const int t = threadIdx.x;
  const int g = t >> 6, lane = t & 63;
  const int gg = __builtin_amdgcn_readfirstlane(g);
  const int b = blockIdx.x & 7;
  const int rr = blockIdx.x >> 3;
  const int qt = rr >> 1, ch = rr & 1;
  const int qbase = qt * 64;

  float qreg[8];
  {
    const float* Qp = Qg + (size_t)(b * 2048 + qbase + lane) * 8;
    float4 a = *(const float4*)Qp;
    float4 c = *(const float4*)(Qp + 4);
    qreg[0] = a.x; qreg[1] = a.y; qreg[2] = a.z; qreg[3] = a.w;
    qreg[4] = c.x; qreg[5] = c.y; qreg[6] = c.z; qreg[7] = c.w;
  }
  const float* Kp = Kg + (size_t)b * (2048 * 8);
  const unsigned short* Vb = Vg + (size_t)b * 1048576;

  char* Pb = smem;
  float* red = (float*)(smem + 16896);
  float* fin = (float*)(smem + 18944);

  // ---- prepass: row max of |s| ; wave g covers keys [g*256,(g+1)*256) (scalar K) ----
  float amax = 0.f;
  {
    const float* kp0 = Kp + (size_t)gg * 2048;
    for (int it = 0; it < 32; ++it){
      const float* kb = kp0 + it * 64;
#pragma unroll
      for (int j = 0; j < 8; ++j){
        float4 k0 = *(const float4*)(kb + j * 8);
        float4 k1 = *(const float4*)(kb + j * 8 + 4);
        amax = fmaxf(amax, fabsf(dot8(qreg, k0, k1)));
      }
    }
  }
  red[g * 64 + lane] = amax;
  __syncthreads();
  float am = red[lane];
#pragma unroll
  for (int gi = 1; gi < 8; ++gi) am = fmaxf(am, red[gi * 64 + lane]);
  float mreg;
  { float s2 = am * am; float s4 = s2 * s2; mreg = s4 * s4; }

  float lp = 0.f;
  const int pwr = (gg ^ (lane & 7)) << 4;   // P write chunk offset (conflict-free)

  auto score = [&](int tt, int sel){
    const float* kb = Kp + (size_t)(tt * 64 + gg * 8) * 8;
    float e[8];
#pragma unroll
    for (int j = 0; j < 8; ++j){
      float4 k0 = *(const float4*)(kb + j * 8);
      float4 k1 = *(const float4*)(kb + j * 8 + 4);
      float s = dot8(qreg, k0, k1);
      float s2 = s * s; float s4 = s2 * s2; float p = s4 * s4;
      e[j] = __expf(p - mreg);
      lp += e[j];
    }
    uint4 pkd;
    pkd.x = pk2bf(e[0], e[1]); pkd.y = pk2bf(e[2], e[3]);
    pkd.z = pk2bf(e[4], e[5]); pkd.w = pk2bf(e[6], e[7]);
    *(uint4*)(Pb + sel * 8192 + lane * 128 + pwr) = pkd;
  };

  auto vload = [&](int tt, s16x8_t vf[2][2]){
    const unsigned short* vb = Vb + (size_t)tt * 32768;
#pragma unroll
    for (int n = 0; n < 2; ++n){
      int cg = ch * 256 + g * 32 + n * 16 + (lane & 15);
#pragma unroll
      for (int ks = 0; ks < 2; ++ks)
        vf[n][ks] = *(const s16x8_t*)(vb + cg * 64 + (ks * 4 + (lane >> 4)) * 8);
    }
  };

  f32x4_t acc[4][2];
#pragma unroll
  for (int mm = 0; mm < 4; ++mm)
#pragma unroll
    for (int n = 0; n < 2; ++n)
      acc[mm][n] = (f32x4_t){0.f, 0.f, 0.f, 0.f};

  auto mfma_tile = [&](int sel, s16x8_t vf[2][2]){
#pragma unroll
    for (int ks = 0; ks < 2; ++ks){
      s16x8_t a[4];
#pragma unroll
      for (int mm = 0; mm < 4; ++mm){
        int row = mm * 16 + (lane & 15);
        int chn = (ks * 4 + (lane >> 4)) ^ (row & 7);
        a[mm] = *(const s16x8_t*)(Pb + sel * 8192 + row * 128 + (chn << 4));
      }
#pragma unroll
      for (int mm = 0; mm < 4; ++mm)
#pragma unroll
        for (int n = 0; n < 2; ++n)
          acc[mm][n] = __builtin_amdgcn_mfma_f32_16x16x32_bf16(a[mm], vf[n][ks], acc[mm][n], 0, 0, 0);
    }
  };

  s16x8_t vfA[2][2], vfB[2][2];
  score(0, 0);
  vload(0, vfA);
  __syncthreads();

  for (int itp = 0; itp < 16; ++itp){
    const int tt0 = itp * 2;
    // tile A (sel 0) consumes vfA
    vload(tt0 + 1, vfB);
    mfma_tile(0, vfA);
    score(tt0 + 1, 1);
    __syncthreads();
    // tile B (sel 1) consumes vfB
    const int tt1 = tt0 + 1;
    if (tt1 + 1 < 32){
      vload(tt1 + 1, vfA);
      mfma_tile(1, vfB);
      score(tt1 + 1, 0);
    } else {
      mfma_tile(1, vfB);
    }
    __syncthreads();
  }

  // ---- softmax denominator: sum lp across the 8 waves per row ----
  red[g * 64 + lane] = lp;
  __syncthreads();
  if (t < 64){
    float s = red[t];
#pragma unroll
    for (int gi = 1; gi < 8; ++gi) s += red[gi * 64 + t];
    fin[t] = 1.f / s;
  }
  __syncthreads();

  // ---- epilogue: 4 rounds of 16 rows x 256 cols via LDS transpose ----
  float* img = (float*)smem;
#pragma unroll
  for (int mm = 0; mm < 4; ++mm){
    float linv[4];
#pragma unroll
    for (int j = 0; j < 4; ++j)
      linv[j] = fin[mm * 16 + ((lane >> 4) << 2) + j];
#pragma unroll
    for (int n = 0; n < 2; ++n){
      int colL = g * 32 + n * 16 + (lane & 15);
#pragma unroll
      for (int j = 0; j < 4; ++j){
        int r16 = ((lane >> 4) << 2) + j;
        img[r16 * 260 + colL] = acc[mm][n][j] * linv[j];
      }
    }
    __syncthreads();
#pragma unroll
    for (int i = 0; i < 2; ++i){
      int idx = i * 512 + t;
      int r16 = idx >> 6, c4 = idx & 63;
      float4 v = *(const float4*)(img + r16 * 260 + c4 * 4);
      *(float4*)(Out + (size_t)(b * 2048 + qbase + mm * 16 + r16) * 512 + ch * 256 + c4 * 4) = v;
    }
    __syncthreads();
  }
}

extern "C" void kernel_launch(void* const* d_in, const int* in_sizes, int n_in,
                              void* d_out, int out_size, void* d_ws, size_t ws_size,
                              hipStream_t stream){
  const float* In = (const float*)d_in[0];
  const float* Wq = (const float*)d_in[1];
  const float* Wk = (const float*)d_in[2];
  const float* Wv = (const float*)d_in[3];
  // power (d_in[4]) is the constant 8; hardcoded as three squarings.
  char* ws = (char*)d_ws;
  unsigned short* WvT = (unsigned short*)(ws);
  float* Q            = (float*)(ws + 524288);
  float* K            = (float*)(ws + 1048576);
  unsigned short* Vg  = (unsigned short*)(ws + 1572864);
  float* Out = (float*)d_out;

  hipLaunchKernelGGL(k_wvT,   dim3(64),   dim3(256), 0, stream, Wv, WvT);
  hipLaunchKernelGGL(k_qk,    dim3(1024), dim3(256), 0, stream, In, Wq, Wk, Q, K);
  hipLaunchKernelGGL(k_vproj, dim3(512),  dim3(256), 0, stream, In, WvT, Vg);
  hipLaunchKernelGGL(k_attn,  dim3(512),  dim3(512), 0, stream, Q, K, Vg, Out);
}